// Round 4
// baseline (627.263 us; speedup 1.0000x reference)
//
#include <hip/hip_runtime.h>

#define N_VOX 100000
#define K_OFF 27
#define M_PAIR 60000
#define NPAIR (K_OFF * M_PAIR)
#define CIN 64
#define COUT 64
#define BN_EPS 1e-5f

typedef __attribute__((ext_vector_type(8))) short bf16x8;
typedef __attribute__((ext_vector_type(8))) unsigned short u16x8;
typedef __attribute__((ext_vector_type(4))) float f32x4;

__device__ __forceinline__ unsigned short f32_to_bf16(float f) {
    unsigned int u = __float_as_uint(f);
    u += 0x7FFFu + ((u >> 16) & 1u);
    return (unsigned short)(u >> 16);
}
__device__ __forceinline__ float bf16_to_f32(unsigned short b) {
    return __uint_as_float(((unsigned int)b) << 16);
}

// ---------- prep ----------

// feats fp32 -> bf16; optionally zero d_out (only the atomic fallback needs it).
__global__ __launch_bounds__(256) void prep_feats_kernel(
    const float* __restrict__ feats, unsigned short* __restrict__ fb,
    float* __restrict__ out, int zero_out)
{
    const int e4 = (blockIdx.x * blockDim.x + threadIdx.x) * 4;
    if (e4 >= N_VOX * CIN) return;
    const float4 v = *(const float4*)(feats + e4);
    ushort4 b;
    b.x = f32_to_bf16(v.x);
    b.y = f32_to_bf16(v.y);
    b.z = f32_to_bf16(v.z);
    b.w = f32_to_bf16(v.w);
    *(ushort4*)(fb + e4) = b;
    if (zero_out) *(float4*)(out + e4) = make_float4(0.f, 0.f, 0.f, 0.f);
}

// W[k][i][c] fp32 -> Wt[k][c][i] bf16.
__global__ __launch_bounds__(256) void prep_w_kernel(
    const float* __restrict__ W, unsigned short* __restrict__ Wt)
{
    const int e = blockIdx.x * blockDim.x + threadIdx.x;
    if (e >= K_OFF * CIN * COUT) return;
    const int k = e / (CIN * COUT);
    const int r = e % (CIN * COUT);
    const int i = r / COUT;
    const int c = r % COUT;
    Wt[k * CIN * COUT + c * CIN + i] = f32_to_bf16(W[e]);
}

// ---------- counting sort by out_idx ----------

__global__ __launch_bounds__(256) void hist_kernel(
    const int* __restrict__ oix, int* __restrict__ cnt)
{
    const int e = blockIdx.x * blockDim.x + threadIdx.x;
    if (e < NPAIR) atomicAdd(&cnt[oix[e]], 1);
}

// Single-block exclusive scan over N_VOX counts -> offs[N_VOX+1] and cursor copy.
__global__ __launch_bounds__(1024) void scan_kernel(
    const int* __restrict__ cnt, int* __restrict__ offs, int* __restrict__ cursor)
{
    __shared__ int part[1024];
    const int t = threadIdx.x;
    const int CH = 98;                      // 1024*98 = 100352 >= N_VOX
    const int b0 = t * CH;
    int s = 0;
    for (int i = 0; i < CH; ++i) {
        const int idx = b0 + i;
        if (idx < N_VOX) s += cnt[idx];
    }
    part[t] = s;
    __syncthreads();
    for (int o = 1; o < 1024; o <<= 1) {    // Hillis-Steele inclusive scan
        int v = (t >= o) ? part[t - o] : 0;
        __syncthreads();
        part[t] += v;
        __syncthreads();
    }
    int ex = (t == 0) ? 0 : part[t - 1];
    for (int i = 0; i < CH; ++i) {
        const int idx = b0 + i;
        if (idx < N_VOX) {
            offs[idx] = ex;
            cursor[idx] = ex;
            ex += cnt[idx];
        }
    }
    if (t == 1023) offs[N_VOX] = part[1023];
}

// Sorted slot for each pair (order within a voxel is irrelevant: we sum).
__global__ __launch_bounds__(256) void pos_kernel(
    const int* __restrict__ oix, int* __restrict__ cursor, int* __restrict__ pos)
{
    const int e = blockIdx.x * blockDim.x + threadIdx.x;
    if (e < NPAIR) pos[e] = atomicAdd(&cursor[oix[e]], 1);
}

// ---------- phase A: gather-GEMM, write contribs to sorted slots ----------
// One wave per 16 pairs, 30 contiguous tiles/wave, 125 active waves per k
// (padded to 128 so __syncthreads trip count is block-uniform).
__global__ __launch_bounds__(256) void conv_scatter_kernel(
    const unsigned short* __restrict__ fb, const unsigned short* __restrict__ Wt,
    const int* __restrict__ in_idx, const int* __restrict__ pos_of_pair,
    unsigned short* __restrict__ contrib)
{
    __shared__ alignas(16) unsigned short lds[4][16 * 72];  // 72: pad for LDS banks
    const int k = blockIdx.y;
    const int lane = threadIdx.x & 63;
    const int wid = threadIdx.x >> 6;
    const int w = blockIdx.x * 4 + wid;     // 0..127
    const bool active = (w < 125);
    const int col = lane & 15;
    const int quad = lane >> 4;
    unsigned short* L = lds[wid];

    // B frags: B[kk][n], n=lane&15, kk=quad*8+j; Wt[k][c][i] keeps j contiguous.
    bf16x8 Bf[4][2];
    const short* Wk = (const short*)(Wt + k * CIN * COUT);
#pragma unroll
    for (int t = 0; t < 4; ++t) {
        const short* p = Wk + (t * 16 + col) * CIN + quad * 8;
        Bf[t][0] = *(const bf16x8*)(p);
        Bf[t][1] = *(const bf16x8*)(p + 32);
    }

    const int base = k * M_PAIR;
    for (int it = 0; it < 30; ++it) {
        const int tile = active ? (w * 30 + it) : 0;
        const int m0 = base + tile * 16;

        const int rin = in_idx[m0 + col];
        const short* fp = (const short*)fb + (size_t)rin * CIN + quad * 8;
        const bf16x8 A0 = *(const bf16x8*)(fp);
        const bf16x8 A1 = *(const bf16x8*)(fp + 32);

        f32x4 acc[4];
#pragma unroll
        for (int t = 0; t < 4; ++t) {
            f32x4 z = {0.f, 0.f, 0.f, 0.f};
            acc[t] = __builtin_amdgcn_mfma_f32_16x16x32_bf16(A0, Bf[t][0], z, 0, 0, 0);
            acc[t] = __builtin_amdgcn_mfma_f32_16x16x32_bf16(A1, Bf[t][1], acc[t], 0, 0, 0);
        }

        // C/D layout (cout = t*16+col, row m = quad*4+r) -> LDS [row][cout] bf16.
#pragma unroll
        for (int r = 0; r < 4; ++r) {
            const int row = quad * 4 + r;
#pragma unroll
            for (int t = 0; t < 4; ++t)
                L[row * 72 + t * 16 + col] = f32_to_bf16(acc[t][r]);
        }
        __syncthreads();
        // Write back: 8 lanes per 128B row -> full-line stores to sorted slot.
#pragma unroll
        for (int itr = 0; itr < 2; ++itr) {
            const int row = itr * 8 + (lane >> 3);
            const int chunk = lane & 7;
            const int pos = pos_of_pair[m0 + row];
            const u16x8 v = *(const u16x8*)(L + row * 72 + chunk * 8);
            if (active)
                *(u16x8*)(contrib + (size_t)pos * 64 + chunk * 8) = v;
        }
        __syncthreads();
    }
}

// ---------- phase B: streaming segmented sum + fused BN + ReLU ----------
__global__ __launch_bounds__(256) void gather_bn_kernel(
    const unsigned short* __restrict__ contrib, const int* __restrict__ offs,
    const float* __restrict__ gamma, const float* __restrict__ beta,
    const float* __restrict__ mean, const float* __restrict__ var,
    float* __restrict__ out)
{
    const int v = blockIdx.x * 4 + (threadIdx.x >> 6);   // one wave per voxel
    if (v >= N_VOX) return;
    const int lane = threadIdx.x & 63;                   // = output channel
    const int s = offs[v], e = offs[v + 1];

    const unsigned short* p = contrib + (size_t)s * 64 + lane;
    float sum = 0.f;
    int j = s;
    for (; j + 1 < e; j += 2, p += 128)                  // unroll-2 for MLP
        sum += bf16_to_f32(p[0]) + bf16_to_f32(p[64]);
    if (j < e) sum += bf16_to_f32(p[0]);

    const float inv = rsqrtf(var[lane] + BN_EPS);
    const float y = (sum - mean[lane]) * (inv * gamma[lane]) + beta[lane];
    out[(size_t)v * 64 + lane] = fmaxf(y, 0.f);
}

// ---------- fallback (round-3 atomic path, used if ws too small) ----------
__global__ __launch_bounds__(256) void conv_atomic_kernel(
    const unsigned short* __restrict__ fb, const unsigned short* __restrict__ Wt,
    const int* __restrict__ in_idx, const int* __restrict__ out_idx,
    float* __restrict__ out)
{
    const int k = blockIdx.y;
    const int lane = threadIdx.x & 63;
    const int wave = blockIdx.x * 4 + (threadIdx.x >> 6);
    const int col = lane & 15;
    const int quad = lane >> 4;

    bf16x8 Bf[4][2];
    const short* Wk = (const short*)(Wt + k * CIN * COUT);
#pragma unroll
    for (int t = 0; t < 4; ++t) {
        const short* p = Wk + (t * 16 + col) * CIN + quad * 8;
        Bf[t][0] = *(const bf16x8*)(p);
        Bf[t][1] = *(const bf16x8*)(p + 32);
    }
    const int base = k * M_PAIR;
    for (int tile = wave; tile < M_PAIR / 16; tile += 128) {
        const int m0 = base + tile * 16;
        const int rin = in_idx[m0 + col];
        const short* fp = (const short*)fb + (size_t)rin * CIN + quad * 8;
        const bf16x8 A0 = *(const bf16x8*)(fp);
        const bf16x8 A1 = *(const bf16x8*)(fp + 32);
        f32x4 acc[4];
#pragma unroll
        for (int t = 0; t < 4; ++t) {
            f32x4 z = {0.f, 0.f, 0.f, 0.f};
            acc[t] = __builtin_amdgcn_mfma_f32_16x16x32_bf16(A0, Bf[t][0], z, 0, 0, 0);
            acc[t] = __builtin_amdgcn_mfma_f32_16x16x32_bf16(A1, Bf[t][1], acc[t], 0, 0, 0);
        }
        int vo[4];
#pragma unroll
        for (int r = 0; r < 4; ++r) vo[r] = out_idx[m0 + quad * 4 + r];
#pragma unroll
        for (int r = 0; r < 4; ++r) {
            float* op = out + (size_t)vo[r] * COUT + col;
#pragma unroll
            for (int t = 0; t < 4; ++t) atomicAdd(op + t * 16, acc[t][r]);
        }
    }
}

__global__ __launch_bounds__(256) void bn_relu_kernel(
    float* __restrict__ out,
    const float* __restrict__ gamma, const float* __restrict__ beta,
    const float* __restrict__ mean, const float* __restrict__ var)
{
    const int e = blockIdx.x * blockDim.x + threadIdx.x;
    if (e >= N_VOX * COUT) return;
    const int c = e & (COUT - 1);
    const float inv = rsqrtf(var[c] + BN_EPS);
    const float y = (out[e] - mean[c]) * (inv * gamma[c]) + beta[c];
    out[e] = fmaxf(y, 0.f);
}

// ---------- host ----------
extern "C" void kernel_launch(void* const* d_in, const int* in_sizes, int n_in,
                              void* d_out, int out_size, void* d_ws, size_t ws_size,
                              hipStream_t stream) {
    const float* feats = (const float*)d_in[0];
    const float* W     = (const float*)d_in[1];
    const float* gamma = (const float*)d_in[2];
    const float* beta  = (const float*)d_in[3];
    const float* rmean = (const float*)d_in[4];
    const float* rvar  = (const float*)d_in[5];
    const int* in_idx  = (const int*)d_in[6];
    const int* out_idx = (const int*)d_in[7];
    float* out = (float*)d_out;

    char* ws = (char*)d_ws;
    size_t off = 0;
    auto alloc = [&](size_t bytes) {
        size_t p = off;
        off = (off + bytes + 255) & ~(size_t)255;
        return p;
    };
    const size_t o_fb  = alloc((size_t)N_VOX * CIN * 2);
    const size_t o_wt  = alloc((size_t)K_OFF * CIN * COUT * 2);
    const size_t o_cnt = alloc((size_t)N_VOX * 4);
    const size_t o_off = alloc((size_t)(N_VOX + 1) * 4);
    const size_t o_cur = alloc((size_t)N_VOX * 4);
    const size_t o_pos = alloc((size_t)NPAIR * 4);
    const size_t o_ctr = alloc((size_t)NPAIR * COUT * 2);
    const bool big = (ws_size >= off);     // constant across calls -> graph-safe

    unsigned short* fb  = (unsigned short*)(ws + o_fb);
    unsigned short* Wt  = (unsigned short*)(ws + o_wt);
    int* cnt            = (int*)(ws + o_cnt);
    int* offs           = (int*)(ws + o_off);
    int* cursor         = (int*)(ws + o_cur);
    int* pos            = (int*)(ws + o_pos);
    unsigned short* ctr = (unsigned short*)(ws + o_ctr);

    const int n_vec4 = (N_VOX * CIN) / 4;
    prep_feats_kernel<<<(n_vec4 + 255) / 256, 256, 0, stream>>>(feats, fb, out, big ? 0 : 1);
    const int wtot = K_OFF * CIN * COUT;
    prep_w_kernel<<<(wtot + 255) / 256, 256, 0, stream>>>(W, Wt);

    if (big) {
        hipMemsetAsync(cnt, 0, (size_t)N_VOX * 4, stream);
        hist_kernel<<<(NPAIR + 255) / 256, 256, 0, stream>>>(out_idx, cnt);
        scan_kernel<<<1, 1024, 0, stream>>>(cnt, offs, cursor);
        pos_kernel<<<(NPAIR + 255) / 256, 256, 0, stream>>>(out_idx, cursor, pos);
        conv_scatter_kernel<<<dim3(32, K_OFF), 256, 0, stream>>>(fb, Wt, in_idx, pos, ctr);
        gather_bn_kernel<<<(N_VOX + 3) / 4, 256, 0, stream>>>(ctr, offs, gamma, beta, rmean, rvar, out);
    } else {
        conv_atomic_kernel<<<dim3(32, K_OFF), 256, 0, stream>>>(fb, Wt, in_idx, out_idx, out);
        const int total = N_VOX * COUT;
        bn_relu_kernel<<<(total + 255) / 256, 256, 0, stream>>>(out, gamma, beta, rmean, rvar);
    }
}

// Round 5
// 473.579 us; speedup vs baseline: 1.3245x; 1.3245x over previous
//
#include <hip/hip_runtime.h>

#define N_VOX 100000
#define K_OFF 27
#define M_PAIR 60000
#define NPAIR (K_OFF * M_PAIR)
#define CIN 64
#define COUT 64
#define BN_EPS 1e-5f

typedef __attribute__((ext_vector_type(8))) short bf16x8;
typedef __attribute__((ext_vector_type(8))) unsigned short u16x8;
typedef __attribute__((ext_vector_type(4))) float f32x4;

__device__ __forceinline__ unsigned short f32_to_bf16(float f) {
    unsigned int u = __float_as_uint(f);
    u += 0x7FFFu + ((u >> 16) & 1u);
    return (unsigned short)(u >> 16);
}
__device__ __forceinline__ float bf16_to_f32(unsigned short b) {
    return __uint_as_float(((unsigned int)b) << 16);
}

// ---------- prep ----------

__global__ __launch_bounds__(256) void prep_feats_kernel(
    const float* __restrict__ feats, unsigned short* __restrict__ fb,
    float* __restrict__ out, int zero_out)
{
    const int e4 = (blockIdx.x * blockDim.x + threadIdx.x) * 4;
    if (e4 >= N_VOX * CIN) return;
    const float4 v = *(const float4*)(feats + e4);
    ushort4 b;
    b.x = f32_to_bf16(v.x);
    b.y = f32_to_bf16(v.y);
    b.z = f32_to_bf16(v.z);
    b.w = f32_to_bf16(v.w);
    *(ushort4*)(fb + e4) = b;
    if (zero_out) *(float4*)(out + e4) = make_float4(0.f, 0.f, 0.f, 0.f);
}

// W[k][i][c] fp32 -> Wt[k][c][i] bf16.
__global__ __launch_bounds__(256) void prep_w_kernel(
    const float* __restrict__ W, unsigned short* __restrict__ Wt)
{
    const int e = blockIdx.x * blockDim.x + threadIdx.x;
    if (e >= K_OFF * CIN * COUT) return;
    const int k = e / (CIN * COUT);
    const int r = e % (CIN * COUT);
    const int i = r / COUT;
    const int c = r % COUT;
    Wt[k * CIN * COUT + c * CIN + i] = f32_to_bf16(W[e]);
}

// ---------- CSR build (no global scan needed) ----------

__global__ __launch_bounds__(256) void hist_kernel(
    const int* __restrict__ oix, int* __restrict__ cnt)
{
    const int e = blockIdx.x * blockDim.x + threadIdx.x;
    if (e < NPAIR) atomicAdd(&cnt[oix[e]], 1);
}

// Segment allocation: segments need not be in voxel order, so a per-block
// LDS scan + ONE atomicAdd on a global allocator per block (391 total)
// replaces the 265us single-block global scan.
__global__ __launch_bounds__(256) void alloc_kernel(
    const int* __restrict__ cnt, int* __restrict__ total,
    int* __restrict__ seg, int* __restrict__ cursor)
{
    __shared__ int part[256];
    __shared__ int bbase;
    const int t = threadIdx.x;
    const int v = blockIdx.x * 256 + t;
    const int c = (v < N_VOX) ? cnt[v] : 0;
    part[t] = c;
    __syncthreads();
    for (int o = 1; o < 256; o <<= 1) {       // Hillis-Steele inclusive scan
        int x = (t >= o) ? part[t - o] : 0;
        __syncthreads();
        part[t] += x;
        __syncthreads();
    }
    if (t == 255) bbase = atomicAdd(total, part[255]);
    __syncthreads();
    if (v < N_VOX) {
        const int excl = part[t] - c;
        seg[v] = bbase + excl;
        cursor[v] = bbase + excl;
    }
}

// sorted_pid[slot] = pair id, grouped per out-voxel segment.
__global__ __launch_bounds__(256) void scatter_pid_kernel(
    const int* __restrict__ oix, int* __restrict__ cursor, int* __restrict__ spid)
{
    const int e = blockIdx.x * blockDim.x + threadIdx.x;
    if (e < NPAIR) spid[atomicAdd(&cursor[oix[e]], 1)] = e;
}

// ---------- phase A: gather-GEMM, SEQUENTIAL contrib writes ----------
// One wave per 16 pairs, 30 tiles/wave, 125 active waves per k.
// LDS slab is wave-private -> no __syncthreads anywhere.
__global__ __launch_bounds__(256) void conv_seq_kernel(
    const unsigned short* __restrict__ fb, const unsigned short* __restrict__ Wt,
    const int* __restrict__ in_idx, unsigned short* __restrict__ contrib)
{
    __shared__ alignas(16) unsigned short lds[4][16 * 72];
    const int k = blockIdx.y;
    const int lane = threadIdx.x & 63;
    const int wid = threadIdx.x >> 6;
    const int w = blockIdx.x * 4 + wid;
    if (w >= 125) return;                     // no barriers -> safe early exit
    const int col = lane & 15;
    const int quad = lane >> 4;
    unsigned short* L = lds[wid];

    bf16x8 Bf[4][2];
    const short* Wk = (const short*)(Wt + k * CIN * COUT);
#pragma unroll
    for (int t = 0; t < 4; ++t) {
        const short* p = Wk + (t * 16 + col) * CIN + quad * 8;
        Bf[t][0] = *(const bf16x8*)(p);
        Bf[t][1] = *(const bf16x8*)(p + 32);
    }

    const int base = k * M_PAIR;
    for (int it = 0; it < 30; ++it) {
        const int p0 = base + (w * 30 + it) * 16;   // global pair id of row 0

        const int rin = in_idx[p0 + col];
        const short* fp = (const short*)fb + (size_t)rin * CIN + quad * 8;
        const bf16x8 A0 = *(const bf16x8*)(fp);
        const bf16x8 A1 = *(const bf16x8*)(fp + 32);

        f32x4 acc[4];
#pragma unroll
        for (int t = 0; t < 4; ++t) {
            f32x4 z = {0.f, 0.f, 0.f, 0.f};
            acc[t] = __builtin_amdgcn_mfma_f32_16x16x32_bf16(A0, Bf[t][0], z, 0, 0, 0);
            acc[t] = __builtin_amdgcn_mfma_f32_16x16x32_bf16(A1, Bf[t][1], acc[t], 0, 0, 0);
        }

        // C/D layout (cout = t*16+col, row = quad*4+r) -> LDS [row][72].
#pragma unroll
        for (int r = 0; r < 4; ++r) {
            const int row = quad * 4 + r;
#pragma unroll
            for (int t = 0; t < 4; ++t)
                L[row * 72 + t * 16 + col] = f32_to_bf16(acc[t][r]);
        }
        // Tile = 16 rows x 128B = 2KB contiguous at contrib[p0*64].
        // Two 1KB wave-stores (16B/lane), intra-wave lgkmcnt orders LDS.
        unsigned short* dst = contrib + (size_t)p0 * 64;
        const int srow = lane >> 3, scol = (lane & 7) * 8;
        const u16x8 v0 = *(const u16x8*)(L + srow * 72 + scol);
        const u16x8 v1 = *(const u16x8*)(L + (8 + srow) * 72 + scol);
        *(u16x8*)(dst + lane * 8) = v0;
        *(u16x8*)(dst + 512 + lane * 8) = v1;
    }
}

// ---------- phase B: per-voxel gather of contrib rows + BN + ReLU ----------
__global__ __launch_bounds__(256) void gather_bn_kernel(
    const unsigned short* __restrict__ contrib, const int* __restrict__ seg,
    const int* __restrict__ cnt, const int* __restrict__ spid,
    const float* __restrict__ gamma, const float* __restrict__ beta,
    const float* __restrict__ mean, const float* __restrict__ var,
    float* __restrict__ out)
{
    const int v = blockIdx.x * 4 + (threadIdx.x >> 6);
    if (v >= N_VOX) return;
    const int lane = threadIdx.x & 63;       // = output channel
    const int s = seg[v];
    const int e = s + cnt[v];

    float s0 = 0.f, s1 = 0.f;
    int j = s;
    for (; j + 1 < e; j += 2) {
        const int pa = __builtin_amdgcn_readfirstlane(spid[j]);
        const int pb = __builtin_amdgcn_readfirstlane(spid[j + 1]);
        s0 += bf16_to_f32(contrib[(size_t)pa * 64 + lane]);
        s1 += bf16_to_f32(contrib[(size_t)pb * 64 + lane]);
    }
    if (j < e) {
        const int pa = __builtin_amdgcn_readfirstlane(spid[j]);
        s0 += bf16_to_f32(contrib[(size_t)pa * 64 + lane]);
    }
    const float sum = s0 + s1;
    const float inv = rsqrtf(var[lane] + BN_EPS);
    const float y = (sum - mean[lane]) * (inv * gamma[lane]) + beta[lane];
    out[(size_t)v * 64 + lane] = fmaxf(y, 0.f);
}

// ---------- fallback (atomic path, used if ws too small) ----------
__global__ __launch_bounds__(256) void conv_atomic_kernel(
    const unsigned short* __restrict__ fb, const unsigned short* __restrict__ Wt,
    const int* __restrict__ in_idx, const int* __restrict__ out_idx,
    float* __restrict__ out)
{
    const int k = blockIdx.y;
    const int lane = threadIdx.x & 63;
    const int wave = blockIdx.x * 4 + (threadIdx.x >> 6);
    const int col = lane & 15;
    const int quad = lane >> 4;
    bf16x8 Bf[4][2];
    const short* Wk = (const short*)(Wt + k * CIN * COUT);
#pragma unroll
    for (int t = 0; t < 4; ++t) {
        const short* p = Wk + (t * 16 + col) * CIN + quad * 8;
        Bf[t][0] = *(const bf16x8*)(p);
        Bf[t][1] = *(const bf16x8*)(p + 32);
    }
    const int base = k * M_PAIR;
    for (int tile = wave; tile < M_PAIR / 16; tile += 128) {
        const int m0 = base + tile * 16;
        const int rin = in_idx[m0 + col];
        const short* fp = (const short*)fb + (size_t)rin * CIN + quad * 8;
        const bf16x8 A0 = *(const bf16x8*)(fp);
        const bf16x8 A1 = *(const bf16x8*)(fp + 32);
        f32x4 acc[4];
#pragma unroll
        for (int t = 0; t < 4; ++t) {
            f32x4 z = {0.f, 0.f, 0.f, 0.f};
            acc[t] = __builtin_amdgcn_mfma_f32_16x16x32_bf16(A0, Bf[t][0], z, 0, 0, 0);
            acc[t] = __builtin_amdgcn_mfma_f32_16x16x32_bf16(A1, Bf[t][1], acc[t], 0, 0, 0);
        }
        int vo[4];
#pragma unroll
        for (int r = 0; r < 4; ++r) vo[r] = out_idx[m0 + quad * 4 + r];
#pragma unroll
        for (int r = 0; r < 4; ++r) {
            float* op = out + (size_t)vo[r] * COUT + col;
#pragma unroll
            for (int t = 0; t < 4; ++t) atomicAdd(op + t * 16, acc[t][r]);
        }
    }
}

__global__ __launch_bounds__(256) void bn_relu_kernel(
    float* __restrict__ out,
    const float* __restrict__ gamma, const float* __restrict__ beta,
    const float* __restrict__ mean, const float* __restrict__ var)
{
    const int e = blockIdx.x * blockDim.x + threadIdx.x;
    if (e >= N_VOX * COUT) return;
    const int c = e & (COUT - 1);
    const float inv = rsqrtf(var[c] + BN_EPS);
    const float y = (out[e] - mean[c]) * (inv * gamma[c]) + beta[c];
    out[e] = fmaxf(y, 0.f);
}

// ---------- host ----------
extern "C" void kernel_launch(void* const* d_in, const int* in_sizes, int n_in,
                              void* d_out, int out_size, void* d_ws, size_t ws_size,
                              hipStream_t stream) {
    const float* feats = (const float*)d_in[0];
    const float* W     = (const float*)d_in[1];
    const float* gamma = (const float*)d_in[2];
    const float* beta  = (const float*)d_in[3];
    const float* rmean = (const float*)d_in[4];
    const float* rvar  = (const float*)d_in[5];
    const int* in_idx  = (const int*)d_in[6];
    const int* out_idx = (const int*)d_in[7];
    float* out = (float*)d_out;

    char* ws = (char*)d_ws;
    size_t off = 0;
    auto alloc = [&](size_t bytes) {
        size_t p = off;
        off = (off + bytes + 255) & ~(size_t)255;
        return p;
    };
    const size_t o_fb   = alloc((size_t)N_VOX * CIN * 2);
    const size_t o_wt   = alloc((size_t)K_OFF * CIN * COUT * 2);
    const size_t o_cnt  = alloc((size_t)N_VOX * 4);
    const size_t o_tot  = alloc(4);
    const size_t o_seg  = alloc((size_t)N_VOX * 4);
    const size_t o_cur  = alloc((size_t)N_VOX * 4);
    const size_t o_pid  = alloc((size_t)NPAIR * 4);
    const size_t o_ctr  = alloc((size_t)NPAIR * COUT * 2);
    const bool big = (ws_size >= off);       // constant across calls -> graph-safe

    unsigned short* fb  = (unsigned short*)(ws + o_fb);
    unsigned short* Wt  = (unsigned short*)(ws + o_wt);
    int* cnt            = (int*)(ws + o_cnt);
    int* total          = (int*)(ws + o_tot);
    int* seg            = (int*)(ws + o_seg);
    int* cursor         = (int*)(ws + o_cur);
    int* spid           = (int*)(ws + o_pid);
    unsigned short* ctr = (unsigned short*)(ws + o_ctr);

    const int n_vec4 = (N_VOX * CIN) / 4;
    prep_feats_kernel<<<(n_vec4 + 255) / 256, 256, 0, stream>>>(feats, fb, out, big ? 0 : 1);
    const int wtot = K_OFF * CIN * COUT;
    prep_w_kernel<<<(wtot + 255) / 256, 256, 0, stream>>>(W, Wt);

    if (big) {
        hipMemsetAsync(cnt, 0, (size_t)N_VOX * 4, stream);
        hipMemsetAsync(total, 0, 4, stream);
        hist_kernel<<<(NPAIR + 255) / 256, 256, 0, stream>>>(out_idx, cnt);
        alloc_kernel<<<(N_VOX + 255) / 256, 256, 0, stream>>>(cnt, total, seg, cursor);
        scatter_pid_kernel<<<(NPAIR + 255) / 256, 256, 0, stream>>>(out_idx, cursor, spid);
        conv_seq_kernel<<<dim3(32, K_OFF), 256, 0, stream>>>(fb, Wt, in_idx, ctr);
        gather_bn_kernel<<<(N_VOX + 3) / 4, 256, 0, stream>>>(ctr, seg, cnt, spid,
                                                              gamma, beta, rmean, rvar, out);
    } else {
        conv_atomic_kernel<<<dim3(32, K_OFF), 256, 0, stream>>>(fb, Wt, in_idx, out_idx, out);
        const int total_e = N_VOX * COUT;
        bn_relu_kernel<<<(total_e + 255) / 256, 256, 0, stream>>>(out, gamma, beta, rmean, rvar);
    }
}

// Round 6
// 363.883 us; speedup vs baseline: 1.7238x; 1.3015x over previous
//
#include <hip/hip_runtime.h>

#define N_VOX 100000
#define K_OFF 27
#define M_PAIR 60000
#define NPAIR (K_OFF * M_PAIR)
#define CIN 64
#define COUT 64
#define BN_EPS 1e-5f

typedef __attribute__((ext_vector_type(8))) short bf16x8;
typedef __attribute__((ext_vector_type(8))) unsigned short u16x8;
typedef __attribute__((ext_vector_type(4))) float f32x4;

__device__ __forceinline__ unsigned short f32_to_bf16(float f) {
    unsigned int u = __float_as_uint(f);
    u += 0x7FFFu + ((u >> 16) & 1u);
    return (unsigned short)(u >> 16);
}
__device__ __forceinline__ float bf16_to_f32(unsigned short b) {
    return __uint_as_float(((unsigned int)b) << 16);
}

// ---------- prep ----------

__global__ __launch_bounds__(256) void prep_feats_kernel(
    const float* __restrict__ feats, unsigned short* __restrict__ fb,
    float* __restrict__ out, int zero_out)
{
    const int e4 = (blockIdx.x * blockDim.x + threadIdx.x) * 4;
    if (e4 >= N_VOX * CIN) return;
    const float4 v = *(const float4*)(feats + e4);
    ushort4 b;
    b.x = f32_to_bf16(v.x);
    b.y = f32_to_bf16(v.y);
    b.z = f32_to_bf16(v.z);
    b.w = f32_to_bf16(v.w);
    *(ushort4*)(fb + e4) = b;
    if (zero_out) *(float4*)(out + e4) = make_float4(0.f, 0.f, 0.f, 0.f);
}

// W[k][i][c] fp32 -> Wt[k][c][i] bf16.
__global__ __launch_bounds__(256) void prep_w_kernel(
    const float* __restrict__ W, unsigned short* __restrict__ Wt)
{
    const int e = blockIdx.x * blockDim.x + threadIdx.x;
    if (e >= K_OFF * CIN * COUT) return;
    const int k = e / (CIN * COUT);
    const int r = e % (CIN * COUT);
    const int i = r / COUT;
    const int c = r % COUT;
    Wt[k * CIN * COUT + c * CIN + i] = f32_to_bf16(W[e]);
}

// ---------- CSR build: hist -> per-block alloc -> pos (coalesced) ----------

__global__ __launch_bounds__(256) void hist_kernel(
    const int* __restrict__ oix, int* __restrict__ cnt)
{
    const int e = blockIdx.x * blockDim.x + threadIdx.x;
    if (e < NPAIR) atomicAdd(&cnt[oix[e]], 1);
}

// Per-block LDS scan + one global allocator atomic per block (391 total).
// Segments need not be in voxel order.
__global__ __launch_bounds__(256) void alloc_kernel(
    const int* __restrict__ cnt, int* __restrict__ total,
    int* __restrict__ seg, int* __restrict__ cursor)
{
    __shared__ int part[256];
    __shared__ int bbase;
    const int t = threadIdx.x;
    const int v = blockIdx.x * 256 + t;
    const int c = (v < N_VOX) ? cnt[v] : 0;
    part[t] = c;
    __syncthreads();
    for (int o = 1; o < 256; o <<= 1) {
        int x = (t >= o) ? part[t - o] : 0;
        __syncthreads();
        part[t] += x;
        __syncthreads();
    }
    if (t == 255) bbase = atomicAdd(total, part[255]);
    __syncthreads();
    if (v < N_VOX) {
        const int excl = part[t] - c;
        seg[v] = bbase + excl;
        cursor[v] = bbase + excl;
    }
}

// pos[e] = sorted slot of pair e. Written COALESCED (indexed by e) — the
// random side is only the int atomic on the L2-resident cursor array.
__global__ __launch_bounds__(256) void pos_kernel(
    const int* __restrict__ oix, int* __restrict__ cursor, int* __restrict__ pos)
{
    const int e = blockIdx.x * blockDim.x + threadIdx.x;
    if (e < NPAIR) pos[e] = atomicAdd(&cursor[oix[e]], 1);
}

// ---------- phase A: gather-GEMM, write rows to sorted slots ----------
// One wave per 16 pairs, 30 tiles/wave, 125 active waves per k.
// Wave-private LDS slab -> no __syncthreads. Contrib row = 128B at pos*128,
// covered by 8 lanes x 16B -> full-line stores, no RMW fetch.
__global__ __launch_bounds__(256) void conv_scatter_kernel(
    const unsigned short* __restrict__ fb, const unsigned short* __restrict__ Wt,
    const int* __restrict__ in_idx, const int* __restrict__ pos_of_pair,
    unsigned short* __restrict__ contrib)
{
    __shared__ alignas(16) unsigned short lds[4][16 * 72];
    const int k = blockIdx.y;
    const int lane = threadIdx.x & 63;
    const int wid = threadIdx.x >> 6;
    const int w = blockIdx.x * 4 + wid;
    if (w >= 125) return;
    const int col = lane & 15;
    const int quad = lane >> 4;
    unsigned short* L = lds[wid];

    bf16x8 Bf[4][2];
    const short* Wk = (const short*)(Wt + k * CIN * COUT);
#pragma unroll
    for (int t = 0; t < 4; ++t) {
        const short* p = Wk + (t * 16 + col) * CIN + quad * 8;
        Bf[t][0] = *(const bf16x8*)(p);
        Bf[t][1] = *(const bf16x8*)(p + 32);
    }

    const int base = k * M_PAIR;
    for (int it = 0; it < 30; ++it) {
        const int m0 = base + (w * 30 + it) * 16;

        const int rin = in_idx[m0 + col];
        const short* fp = (const short*)fb + (size_t)rin * CIN + quad * 8;
        const bf16x8 A0 = *(const bf16x8*)(fp);
        const bf16x8 A1 = *(const bf16x8*)(fp + 32);

        f32x4 acc[4];
#pragma unroll
        for (int t = 0; t < 4; ++t) {
            f32x4 z = {0.f, 0.f, 0.f, 0.f};
            acc[t] = __builtin_amdgcn_mfma_f32_16x16x32_bf16(A0, Bf[t][0], z, 0, 0, 0);
            acc[t] = __builtin_amdgcn_mfma_f32_16x16x32_bf16(A1, Bf[t][1], acc[t], 0, 0, 0);
        }

        // C/D layout (cout = t*16+col, row = quad*4+r) -> LDS [row][72].
#pragma unroll
        for (int r = 0; r < 4; ++r) {
            const int row = quad * 4 + r;
#pragma unroll
            for (int t = 0; t < 4; ++t)
                L[row * 72 + t * 16 + col] = f32_to_bf16(acc[t][r]);
        }
        // Writeback: 8 lanes per 128B row; slot = pos_of_pair[pair].
        // Intra-wave LDS write->read ordered by compiler lgkmcnt.
#pragma unroll
        for (int itr = 0; itr < 2; ++itr) {
            const int row = itr * 8 + (lane >> 3);
            const int chunk = lane & 7;
            const int pos = pos_of_pair[m0 + row];
            const u16x8 v = *(const u16x8*)(L + row * 72 + chunk * 8);
            *(u16x8*)(contrib + (size_t)pos * 64 + chunk * 8) = v;
        }
    }
}

// ---------- phase B: streaming segmented sum + fused BN + ReLU ----------
__global__ __launch_bounds__(256) void gather_bn_kernel(
    const unsigned short* __restrict__ contrib, const int* __restrict__ seg,
    const int* __restrict__ cnt,
    const float* __restrict__ gamma, const float* __restrict__ beta,
    const float* __restrict__ mean, const float* __restrict__ var,
    float* __restrict__ out)
{
    const int v = blockIdx.x * 4 + (threadIdx.x >> 6);   // one wave per voxel
    if (v >= N_VOX) return;
    const int lane = threadIdx.x & 63;                   // = output channel
    const int s = seg[v];
    const int n = cnt[v];

    const unsigned short* p = contrib + (size_t)s * 64 + lane;
    float s0 = 0.f, s1 = 0.f, s2 = 0.f, s3 = 0.f;
    int j = 0;
    for (; j + 3 < n; j += 4, p += 256) {
        s0 += bf16_to_f32(p[0]);
        s1 += bf16_to_f32(p[64]);
        s2 += bf16_to_f32(p[128]);
        s3 += bf16_to_f32(p[192]);
    }
    for (; j < n; ++j, p += 64) s0 += bf16_to_f32(p[0]);
    const float sum = (s0 + s1) + (s2 + s3);

    const float inv = rsqrtf(var[lane] + BN_EPS);
    const float y = (sum - mean[lane]) * (inv * gamma[lane]) + beta[lane];
    out[(size_t)v * 64 + lane] = fmaxf(y, 0.f);
}

// ---------- fallback (atomic path, used if ws too small) ----------
__global__ __launch_bounds__(256) void conv_atomic_kernel(
    const unsigned short* __restrict__ fb, const unsigned short* __restrict__ Wt,
    const int* __restrict__ in_idx, const int* __restrict__ out_idx,
    float* __restrict__ out)
{
    const int k = blockIdx.y;
    const int lane = threadIdx.x & 63;
    const int wave = blockIdx.x * 4 + (threadIdx.x >> 6);
    const int col = lane & 15;
    const int quad = lane >> 4;
    bf16x8 Bf[4][2];
    const short* Wk = (const short*)(Wt + k * CIN * COUT);
#pragma unroll
    for (int t = 0; t < 4; ++t) {
        const short* p = Wk + (t * 16 + col) * CIN + quad * 8;
        Bf[t][0] = *(const bf16x8*)(p);
        Bf[t][1] = *(const bf16x8*)(p + 32);
    }
    const int base = k * M_PAIR;
    for (int tile = wave; tile < M_PAIR / 16; tile += 128) {
        const int m0 = base + tile * 16;
        const int rin = in_idx[m0 + col];
        const short* fp = (const short*)fb + (size_t)rin * CIN + quad * 8;
        const bf16x8 A0 = *(const bf16x8*)(fp);
        const bf16x8 A1 = *(const bf16x8*)(fp + 32);
        f32x4 acc[4];
#pragma unroll
        for (int t = 0; t < 4; ++t) {
            f32x4 z = {0.f, 0.f, 0.f, 0.f};
            acc[t] = __builtin_amdgcn_mfma_f32_16x16x32_bf16(A0, Bf[t][0], z, 0, 0, 0);
            acc[t] = __builtin_amdgcn_mfma_f32_16x16x32_bf16(A1, Bf[t][1], acc[t], 0, 0, 0);
        }
        int vo[4];
#pragma unroll
        for (int r = 0; r < 4; ++r) vo[r] = out_idx[m0 + quad * 4 + r];
#pragma unroll
        for (int r = 0; r < 4; ++r) {
            float* op = out + (size_t)vo[r] * COUT + col;
#pragma unroll
            for (int t = 0; t < 4; ++t) atomicAdd(op + t * 16, acc[t][r]);
        }
    }
}

__global__ __launch_bounds__(256) void bn_relu_kernel(
    float* __restrict__ out,
    const float* __restrict__ gamma, const float* __restrict__ beta,
    const float* __restrict__ mean, const float* __restrict__ var)
{
    const int e = blockIdx.x * blockDim.x + threadIdx.x;
    if (e >= N_VOX * COUT) return;
    const int c = e & (COUT - 1);
    const float inv = rsqrtf(var[c] + BN_EPS);
    const float y = (out[e] - mean[c]) * (inv * gamma[c]) + beta[c];
    out[e] = fmaxf(y, 0.f);
}

// ---------- host ----------
extern "C" void kernel_launch(void* const* d_in, const int* in_sizes, int n_in,
                              void* d_out, int out_size, void* d_ws, size_t ws_size,
                              hipStream_t stream) {
    const float* feats = (const float*)d_in[0];
    const float* W     = (const float*)d_in[1];
    const float* gamma = (const float*)d_in[2];
    const float* beta  = (const float*)d_in[3];
    const float* rmean = (const float*)d_in[4];
    const float* rvar  = (const float*)d_in[5];
    const int* in_idx  = (const int*)d_in[6];
    const int* out_idx = (const int*)d_in[7];
    float* out = (float*)d_out;

    char* ws = (char*)d_ws;
    size_t off = 0;
    auto alloc = [&](size_t bytes) {
        size_t p = off;
        off = (off + bytes + 255) & ~(size_t)255;
        return p;
    };
    const size_t o_fb   = alloc((size_t)N_VOX * CIN * 2);
    const size_t o_wt   = alloc((size_t)K_OFF * CIN * COUT * 2);
    const size_t o_cnt  = alloc((size_t)N_VOX * 4);
    const size_t o_tot  = alloc(4);
    const size_t o_seg  = alloc((size_t)N_VOX * 4);
    const size_t o_cur  = alloc((size_t)N_VOX * 4);
    const size_t o_pos  = alloc((size_t)NPAIR * 4);
    const size_t o_ctr  = alloc((size_t)NPAIR * COUT * 2);
    const bool big = (ws_size >= off);       // constant across calls -> graph-safe

    unsigned short* fb  = (unsigned short*)(ws + o_fb);
    unsigned short* Wt  = (unsigned short*)(ws + o_wt);
    int* cnt            = (int*)(ws + o_cnt);
    int* total          = (int*)(ws + o_tot);
    int* seg            = (int*)(ws + o_seg);
    int* cursor         = (int*)(ws + o_cur);
    int* pos            = (int*)(ws + o_pos);
    unsigned short* ctr = (unsigned short*)(ws + o_ctr);

    const int n_vec4 = (N_VOX * CIN) / 4;
    prep_feats_kernel<<<(n_vec4 + 255) / 256, 256, 0, stream>>>(feats, fb, out, big ? 0 : 1);
    const int wtot = K_OFF * CIN * COUT;
    prep_w_kernel<<<(wtot + 255) / 256, 256, 0, stream>>>(W, Wt);

    if (big) {
        hipMemsetAsync(cnt, 0, (size_t)N_VOX * 4, stream);
        hipMemsetAsync(total, 0, 4, stream);
        hist_kernel<<<(NPAIR + 255) / 256, 256, 0, stream>>>(out_idx, cnt);
        alloc_kernel<<<(N_VOX + 255) / 256, 256, 0, stream>>>(cnt, total, seg, cursor);
        pos_kernel<<<(NPAIR + 255) / 256, 256, 0, stream>>>(out_idx, cursor, pos);
        conv_scatter_kernel<<<dim3(32, K_OFF), 256, 0, stream>>>(fb, Wt, in_idx, pos, ctr);
        gather_bn_kernel<<<(N_VOX + 3) / 4, 256, 0, stream>>>(ctr, seg, cnt,
                                                              gamma, beta, rmean, rvar, out);
    } else {
        conv_atomic_kernel<<<dim3(32, K_OFF), 256, 0, stream>>>(fb, Wt, in_idx, out_idx, out);
        const int total_e = N_VOX * COUT;
        bn_relu_kernel<<<(total_e + 255) / 256, 256, 0, stream>>>(out, gamma, beta, rmean, rvar);
    }
}